// Round 14
// baseline (2755.289 us; speedup 1.0000x reference)
//
#include <hip/hip_runtime.h>
#include <hip/hip_bf16.h>
#include <math.h>

#define NB 16384
#define DD 64
#define HH 256
#define NSTEP 63
#define RB 32          // rows per block
#define NT 512         // 8 waves; 75.3 KB LDS -> 2 blocks/CU = 4 waves/SIMD

#define SYW 68         // u32 stride, packed 64-wide bufs (y, actor)
#define SHW 260        // u32 stride, packed 256-wide bufs (h1, h2)

// g_wb layout (ushort units) — weights as hi+lo planes in B-frag order
#define O1H 0
#define O1L 16384
#define O2H 32768
#define O2L 98304
#define O3H 163840
#define O3L 180224
#define AM1H 196608
#define AM1L 200704
#define AM2H 204800
#define AM2L 208896
#define AM3H 212992
#define AM3L 217088
#define AS1H 221184
#define AS1L 225280
#define AS2H 229376
#define AS2L 233472
#define AS3H 237568
#define AS3L 241664
#define WB_SHORTS 245760

// normal cached device memory (d_ws is uncached fine-grained — R10 evidence)
__device__ unsigned short g_wb[WB_SHORTS];

typedef __attribute__((ext_vector_type(8))) short s8v;          // 8 bf16
typedef __attribute__((ext_vector_type(4))) float f4v;          // MFMA acc
typedef __attribute__((ext_vector_type(4))) unsigned int u4v;

#define MFMA(a, b, c) __builtin_amdgcn_mfma_f32_16x16x32_bf16((a), (b), (c), 0, 0, 0)
// 3-term split product: A*B ≈ Ah*Bh + Ah*Bl + Al*Bh   (residual ~2^-17)
#define MM3(acc, ah, al, bh, bl)                                 \
    do {                                                         \
        acc = MFMA(ah, bh, acc);                                 \
        acc = MFMA(ah, bl, acc);                                 \
        acc = MFMA(al, bh, acc);                                 \
    } while (0)

__device__ __forceinline__ unsigned short f2b(float x) {
    return __builtin_bit_cast(unsigned short, (__bf16)x);
}
__device__ __forceinline__ float b2f(unsigned short u) {
    return __builtin_bit_cast(float, (unsigned int)u << 16);
}
// truncation split, 3 VALU ops: hi = upper16(x) (trunc), lo = bf16_trunc(x - hi).
// packed u32 = hi | (lo << 16). Residual ~2^-16 rel (vs 2^-17 RNE) — fine.
__device__ __forceinline__ unsigned int packsplit(float x) {
    const unsigned int xb = __builtin_bit_cast(unsigned int, x);
    const unsigned int hb = xb & 0xFFFF0000u;
    const float lof = x - __builtin_bit_cast(float, hb);
    const unsigned int lb = __builtin_bit_cast(unsigned int, lof);
    // dst = (lo_high16 << 16) | hi_high16   [perm: s[7:4]=A, s[3:0]=B]
    return __builtin_amdgcn_perm(lb, hb, 0x07060302);
}
__device__ __forceinline__ float fast_tanh(float x) {
    float e = __expf(-2.0f * fabsf(x));
    float r = __fdividef(1.0f - e, 1.0f + e);
    return copysignf(r, x);
}
__device__ __forceinline__ float fast_softplus(float x) {
    return fmaxf(x, 0.0f) + __logf(1.0f + __expf(-fabsf(x)));
}
__device__ __forceinline__ float clean_f(float x) { return isfinite(x) ? x : 0.0f; }
__device__ __forceinline__ f4v splat4(float b) { f4v v = {b, b, b, b}; return v; }

// read 8 packed u32 (hi|lo per element), unpack to hi/lo bf16 A-fragments
__device__ __forceinline__ void ldsPK(const unsigned int* p, s8v* hi, s8v* lo) {
    const u4v q0 = *(const u4v*)p;
    const u4v q1 = *(const u4v*)(p + 4);
    union { unsigned int u[4]; s8v v; } H, L;
    H.u[0] = __builtin_amdgcn_perm(q0[1], q0[0], 0x05040100);
    L.u[0] = __builtin_amdgcn_perm(q0[1], q0[0], 0x07060302);
    H.u[1] = __builtin_amdgcn_perm(q0[3], q0[2], 0x05040100);
    L.u[1] = __builtin_amdgcn_perm(q0[3], q0[2], 0x07060302);
    H.u[2] = __builtin_amdgcn_perm(q1[1], q1[0], 0x05040100);
    L.u[2] = __builtin_amdgcn_perm(q1[1], q1[0], 0x07060302);
    H.u[3] = __builtin_amdgcn_perm(q1[3], q1[2], 0x05040100);
    L.u[3] = __builtin_amdgcn_perm(q1[3], q1[2], 0x07060302);
    *hi = H.v; *lo = L.v;
}

// swizzle W[K x N] f32 into B-fragment order, split bf16 hi+lo (RNE), into g_wb
__global__ void prep_kernel(const float* __restrict__ W, int K, int N,
                            int hi_off, int lo_off) {
    const int l = threadIdx.x;            // 64
    const int kcN = K >> 5;
    const int nt = blockIdx.x / kcN;
    const int kc = blockIdx.x % kcN;
    const int col = nt * 16 + (l & 15);
    const int k0 = kc * 32 + ((l >> 4) << 3);
    const size_t base = ((size_t)(nt * kcN + kc) * 64 + l) * 8;
#pragma unroll
    for (int b = 0; b < 8; ++b) {
        float wv = W[(size_t)(k0 + b) * N + col];
        unsigned short h = f2b(wv);
        g_wb[hi_off + base + b] = h;
        g_wb[lo_off + base + b] = f2b(wv - b2f(h));
    }
}

extern "C" __global__ void __launch_bounds__(NT, 4)
ode_sac_kernel(const float* __restrict__ y0,
               const float* __restrict__ tarr,
               const float* __restrict__ noise,
               const float* __restrict__ ob1, const float* __restrict__ ob2,
               const float* __restrict__ ob3,
               const float* __restrict__ amb1, const float* __restrict__ amb2,
               const float* __restrict__ amb3,
               const float* __restrict__ asb1, const float* __restrict__ asb2,
               const float* __restrict__ asb3,
               float* __restrict__ out) {
    // 75264 B total -> 2 blocks/CU (two independent barrier domains)
    __shared__ __align__(16) unsigned int y_pk[RB * SYW];    //  8704 B
    __shared__ __align__(16) unsigned int h1_pk[RB * SHW];   // 33280 B
    __shared__ __align__(16) unsigned int h2_pk[RB * SHW];   // 33280 B
    unsigned int* a1m = h1_pk;                 // [32][SYW] carved from h1
    unsigned int* a1s = h1_pk + RB * SYW;      // 2*RB*SYW = 4352 <= RB*SHW = 8320 OK
    unsigned int* a2m = h2_pk;
    unsigned int* a2s = h2_pk + RB * SYW;

    const int tid = threadIdx.x;
    const int w  = tid >> 6;       // wave 0..7
    const int l  = tid & 63;
    const int lm = l & 15;
    const int lg = l >> 4;
    const int wm = w >> 2;         // row half: rows wm*16..+15
    const int wn = w & 3;          // col quadrant (narrow layers / B3)
    const int row0 = blockIdx.x * RB;
    const int cN = wn * 16 + lm;   // narrow-layer ownership column

    const float dt = tarr[1] - tarr[0];

    const unsigned short* ws = g_wb;
    const s8v* o1h = (const s8v*)(ws + O1H); const s8v* o1l = (const s8v*)(ws + O1L);
    const s8v* o2h = (const s8v*)(ws + O2H); const s8v* o2l = (const s8v*)(ws + O2L);
    const s8v* o3h = (const s8v*)(ws + O3H); const s8v* o3l = (const s8v*)(ws + O3L);
    const s8v* am1h = (const s8v*)(ws + AM1H); const s8v* am1l = (const s8v*)(ws + AM1L);
    const s8v* am2h = (const s8v*)(ws + AM2H); const s8v* am2l = (const s8v*)(ws + AM2L);
    const s8v* am3h = (const s8v*)(ws + AM3H); const s8v* am3l = (const s8v*)(ws + AM3L);
    const s8v* as1h = (const s8v*)(ws + AS1H); const s8v* as1l = (const s8v*)(ws + AS1L);
    const s8v* as2h = (const s8v*)(ws + AS2H); const s8v* as2l = (const s8v*)(ws + AS2L);
    const s8v* as3h = (const s8v*)(ws + AS3H); const s8v* as3l = (const s8v*)(ws + AS3L);

    // biases
    const float b_am1 = amb1[cN], b_am2 = amb2[cN], b_am3 = amb3[cN];
    const float b_as1 = asb1[cN], b_as2 = asb2[cN], b_as3 = asb3[cN];
    const float b_o3  = ob3[cN];
    const float b_o2a = ob2[(w * 2) * 16 + lm];
    const float b_o2b = ob2[(w * 2 + 1) * 16 + lm];
    float b_o1v[4];
#pragma unroll
    for (int nt = 0; nt < 4; ++nt) b_o1v[nt] = ob1[wn * 64 + nt * 16 + lm];

    // y state in registers (exact f32): elem r at row wm*16+lg*4+r, col cN
    float ysr[4];
#pragma unroll
    for (int r = 0; r < 4; ++r) {
        const int row = wm * 16 + lg * 4 + r;
        const float v = y0[(size_t)(row0 + row) * DD + cN];
        ysr[r] = v;
        y_pk[row * SYW + cN] = packsplit(v);
        // out[0] exact from registers (16 lanes cover one 64B segment)
        __builtin_nontemporal_store(v, &out[(size_t)(row0 + row) * DD + cN]);
    }
    __syncthreads();

    for (int t = 0; t < NSTEP; ++t) {
        // noise prefetch (used in P3)
        float ep[4];
#pragma unroll
        for (int r = 0; r < 4; ++r) {
            const int row = wm * 16 + lg * 4 + r;
            ep[r] = __builtin_nontemporal_load(
                &noise[(size_t)t * NB * DD + (size_t)(row0 + row) * DD + cN]);
        }

        // ---------- P1: A1 & S1 = relu(y @ W1 + b), 3-term ----------
        {
            f4v am = splat4(b_am1), as_ = splat4(b_as1);
#pragma unroll
            for (int kc = 0; kc < 2; ++kc) {
                s8v yh, yl;
                ldsPK(&y_pk[(wm * 16 + lm) * SYW + kc * 32 + lg * 8], &yh, &yl);
                const int fb = (wn * 2 + kc) * 64 + l;
                MM3(am, yh, yl, am1h[fb], am1l[fb]);
                MM3(as_, yh, yl, as1h[fb], as1l[fb]);
            }
#pragma unroll
            for (int r = 0; r < 4; ++r) {
                const int row = wm * 16 + lg * 4 + r;
                a1m[row * SYW + cN] = packsplit(fmaxf(am[r], 0.0f));
                a1s[row * SYW + cN] = packsplit(fmaxf(as_[r], 0.0f));
            }
        }
        __syncthreads();

        // ---------- P2: A2 & S2 ----------
        {
            f4v am = splat4(b_am2), as_ = splat4(b_as2);
#pragma unroll
            for (int kc = 0; kc < 2; ++kc) {
                const int k0 = kc * 32 + lg * 8;
                s8v mh, ml, sh, sl;
                ldsPK(&a1m[(wm * 16 + lm) * SYW + k0], &mh, &ml);
                ldsPK(&a1s[(wm * 16 + lm) * SYW + k0], &sh, &sl);
                const int fb = (wn * 2 + kc) * 64 + l;
                MM3(am, mh, ml, am2h[fb], am2l[fb]);
                MM3(as_, sh, sl, as2h[fb], as2l[fb]);
            }
#pragma unroll
            for (int r = 0; r < 4; ++r) {
                const int row = wm * 16 + lg * 4 + r;
                a2m[row * SYW + cN] = packsplit(fmaxf(am[r], 0.0f));
                a2s[row * SYW + cN] = packsplit(fmaxf(as_[r], 0.0f));
            }
        }
        __syncthreads();

        // ---------- P3: A3 & S3 -> u (regs);  B1 -> h1 ----------
        float u[4];
        {
            f4v m3 = splat4(b_am3), s3 = splat4(b_as3);
#pragma unroll
            for (int kc = 0; kc < 2; ++kc) {
                const int k0 = kc * 32 + lg * 8;
                s8v mh, ml, sh, sl;
                ldsPK(&a2m[(wm * 16 + lm) * SYW + k0], &mh, &ml);
                ldsPK(&a2s[(wm * 16 + lm) * SYW + k0], &sh, &sl);
                const int fb = (wn * 2 + kc) * 64 + l;
                MM3(m3, mh, ml, am3h[fb], am3l[fb]);
                MM3(s3, sh, sl, as3h[fb], as3l[fb]);
            }
#pragma unroll
            for (int r = 0; r < 4; ++r) {
                const float mean = clean_f(fast_tanh(m3[r]));
                const float ls   = clean_f(s3[r]);
                const float sd   = fast_softplus(ls);
                u[r] = fast_tanh(mean + sd * ep[r]);
            }
        }
        {   // B1: h1 = tanh(y @ oW1 + ob1); wave: rows wm*16..+15, cols wn*64..+63
            f4v acc[4];
#pragma unroll
            for (int nt = 0; nt < 4; ++nt) acc[nt] = splat4(b_o1v[nt]);
#pragma unroll
            for (int kc = 0; kc < 2; ++kc) {
                s8v yh, yl;
                ldsPK(&y_pk[(wm * 16 + lm) * SYW + kc * 32 + lg * 8], &yh, &yl);
#pragma unroll
                for (int nt = 0; nt < 4; ++nt) {
                    const int fb = (((wn * 4 + nt) * 2) + kc) * 64 + l;
                    MM3(acc[nt], yh, yl, o1h[fb], o1l[fb]);
                }
            }
#pragma unroll
            for (int nt = 0; nt < 4; ++nt)
#pragma unroll
                for (int r = 0; r < 4; ++r) {
                    const int row = wm * 16 + lg * 4 + r;
                    const int col = wn * 64 + nt * 16 + lm;
                    h1_pk[row * SHW + col] = packsplit(fast_tanh(acc[nt][r]));
                }
        }
        __syncthreads();

        // ---------- P4: B2 = softplus(h1 @ oW2 + ob2); wave: 32 rows x cols w*32..+31 ----------
        {
            f4v acc[2][2];
            acc[0][0] = splat4(b_o2a); acc[0][1] = splat4(b_o2b);
            acc[1][0] = splat4(b_o2a); acc[1][1] = splat4(b_o2b);
#pragma unroll
            for (int kc = 0; kc < 8; ++kc) {
                const int k0 = kc * 32 + lg * 8;
                s8v a0h, a0l, a1h_, a1l_;
                ldsPK(&h1_pk[(0 * 16 + lm) * SHW + k0], &a0h, &a0l);
                ldsPK(&h1_pk[(1 * 16 + lm) * SHW + k0], &a1h_, &a1l_);
                const int f0 = ((w * 2 + 0) * 8 + kc) * 64 + l;
                const int f1 = ((w * 2 + 1) * 8 + kc) * 64 + l;
                const s8v bh0 = o2h[f0], bl0 = o2l[f0];
                const s8v bh1 = o2h[f1], bl1 = o2l[f1];
                MM3(acc[0][0], a0h, a0l, bh0, bl0);
                MM3(acc[0][1], a0h, a0l, bh1, bl1);
                MM3(acc[1][0], a1h_, a1l_, bh0, bl0);
                MM3(acc[1][1], a1h_, a1l_, bh1, bl1);
            }
#pragma unroll
            for (int mt = 0; mt < 2; ++mt)
#pragma unroll
                for (int ct = 0; ct < 2; ++ct)
#pragma unroll
                    for (int r = 0; r < 4; ++r) {
                        const int row = mt * 16 + lg * 4 + r;
                        const int col = (w * 2 + ct) * 16 + lm;
                        h2_pk[row * SHW + col] = packsplit(fast_softplus(acc[mt][ct][r]));
                    }
        }
        __syncthreads();

        // ---------- P5: B3 = h2 @ oW3 + ob3 ; y += (f - u)*dt ; out exact ----------
        {
            f4v f3 = splat4(b_o3);
#pragma unroll
            for (int kc = 0; kc < 8; ++kc) {
                s8v ah, al;
                ldsPK(&h2_pk[(wm * 16 + lm) * SHW + kc * 32 + lg * 8], &ah, &al);
                const int fb = (wn * 8 + kc) * 64 + l;
                MM3(f3, ah, al, o3h[fb], o3l[fb]);
            }
#pragma unroll
            for (int r = 0; r < 4; ++r) {
                const int row = wm * 16 + lg * 4 + r;
                const float yn = ysr[r] + (f3[r] - u[r]) * dt;
                ysr[r] = yn;
                y_pk[row * SYW + cN] = packsplit(yn);
                __builtin_nontemporal_store(yn,
                    &out[(size_t)(t + 1) * NB * DD + (size_t)(row0 + row) * DD + cN]);
            }
        }
        __syncthreads();
    }
}

extern "C" void kernel_launch(void* const* d_in, const int* in_sizes, int n_in,
                              void* d_out, int out_size, void* d_ws, size_t ws_size,
                              hipStream_t stream) {
    const float* y0    = (const float*)d_in[0];
    const float* tarr  = (const float*)d_in[1];
    const float* noise = (const float*)d_in[2];
    const float* oW1 = (const float*)d_in[3];  const float* ob1 = (const float*)d_in[4];
    const float* oW2 = (const float*)d_in[5];  const float* ob2 = (const float*)d_in[6];
    const float* oW3 = (const float*)d_in[7];  const float* ob3 = (const float*)d_in[8];
    const float* amW1 = (const float*)d_in[9];  const float* amb1 = (const float*)d_in[10];
    const float* amW2 = (const float*)d_in[11]; const float* amb2 = (const float*)d_in[12];
    const float* amW3 = (const float*)d_in[13]; const float* amb3 = (const float*)d_in[14];
    const float* asW1 = (const float*)d_in[15]; const float* asb1 = (const float*)d_in[16];
    const float* asW2 = (const float*)d_in[17]; const float* asb2 = (const float*)d_in[18];
    const float* asW3 = (const float*)d_in[19]; const float* asb3 = (const float*)d_in[20];
    float* out = (float*)d_out;

    // weight swizzle + hi/lo split into cached __device__ g_wb (step-invariant)
    hipLaunchKernelGGL(prep_kernel, dim3(16 * 2), dim3(64), 0, stream, oW1, 64, 256, O1H, O1L);
    hipLaunchKernelGGL(prep_kernel, dim3(16 * 8), dim3(64), 0, stream, oW2, 256, 256, O2H, O2L);
    hipLaunchKernelGGL(prep_kernel, dim3(4 * 8),  dim3(64), 0, stream, oW3, 256, 64, O3H, O3L);
    hipLaunchKernelGGL(prep_kernel, dim3(4 * 2),  dim3(64), 0, stream, amW1, 64, 64, AM1H, AM1L);
    hipLaunchKernelGGL(prep_kernel, dim3(4 * 2),  dim3(64), 0, stream, amW2, 64, 64, AM2H, AM2L);
    hipLaunchKernelGGL(prep_kernel, dim3(4 * 2),  dim3(64), 0, stream, amW3, 64, 64, AM3H, AM3L);
    hipLaunchKernelGGL(prep_kernel, dim3(4 * 2),  dim3(64), 0, stream, asW1, 64, 64, AS1H, AS1L);
    hipLaunchKernelGGL(prep_kernel, dim3(4 * 2),  dim3(64), 0, stream, asW2, 64, 64, AS2H, AS2L);
    hipLaunchKernelGGL(prep_kernel, dim3(4 * 2),  dim3(64), 0, stream, asW3, 64, 64, AS3H, AS3L);

    hipLaunchKernelGGL(ode_sac_kernel, dim3(NB / RB), dim3(NT), 0, stream,
                       y0, tarr, noise,
                       ob1, ob2, ob3, amb1, amb2, amb3, asb1, asb2, asb3,
                       out);
}

// Round 15
// 1580.713 us; speedup vs baseline: 1.7431x; 1.7431x over previous
//
#include <hip/hip_runtime.h>
#include <hip/hip_bf16.h>
#include <math.h>

#define NB 16384
#define DD 64
#define HH 256
#define NSTEP 63
#define RB 32          // rows per block -> grid 512
#define NT 512         // 8 waves

#define SYW 68         // u32 stride, packed 64-wide bufs (y, actor)
#define SHW 260        // u32 stride, packed 256-wide bufs (h1, h2)

// g_wb layout (ushort units) — UNCHANGED from R14 (prep identical)
#define O1H 0
#define O1L 16384
#define O2H 32768
#define O2L 98304
#define O3H 163840
#define O3L 180224
#define AM1H 196608
#define AM1L 200704
#define AM2H 204800
#define AM2L 208896
#define AM3H 212992
#define AM3L 217088
#define AS1H 221184
#define AS1L 225280
#define AS2H 229376
#define AS2L 233472
#define AS3H 237568
#define AS3L 241664
#define WB_SHORTS 245760

__device__ unsigned short g_wb[WB_SHORTS];   // cached device memory

typedef __attribute__((ext_vector_type(8))) short s8v;
typedef __attribute__((ext_vector_type(4))) float f4v;
typedef __attribute__((ext_vector_type(4))) unsigned int u4v;

#define MFMA(a, b, c) __builtin_amdgcn_mfma_f32_16x16x32_bf16((a), (b), (c), 0, 0, 0)
#define MM3(acc, ah, al, bh, bl)                                 \
    do {                                                         \
        acc = MFMA(ah, bh, acc);                                 \
        acc = MFMA(ah, bl, acc);                                 \
        acc = MFMA(al, bh, acc);                                 \
    } while (0)

__device__ __forceinline__ unsigned short f2b(float x) {
    return __builtin_bit_cast(unsigned short, (__bf16)x);
}
__device__ __forceinline__ float b2f(unsigned short u) {
    return __builtin_bit_cast(float, (unsigned int)u << 16);
}
__device__ __forceinline__ unsigned int packsplit(float x) {
    const unsigned int xb = __builtin_bit_cast(unsigned int, x);
    const unsigned int hb = xb & 0xFFFF0000u;
    const float lof = x - __builtin_bit_cast(float, hb);
    const unsigned int lb = __builtin_bit_cast(unsigned int, lof);
    return __builtin_amdgcn_perm(lb, hb, 0x07060302);
}
__device__ __forceinline__ float fast_tanh(float x) {
    float e = __expf(-2.0f * fabsf(x));
    float r = __fdividef(1.0f - e, 1.0f + e);
    return copysignf(r, x);
}
__device__ __forceinline__ float fast_softplus(float x) {
    return fmaxf(x, 0.0f) + __logf(1.0f + __expf(-fabsf(x)));
}
__device__ __forceinline__ float clean_f(float x) { return isfinite(x) ? x : 0.0f; }
__device__ __forceinline__ f4v splat4(float b) { f4v v = {b, b, b, b}; return v; }

__device__ __forceinline__ void ldsPK(const unsigned int* p, s8v* hi, s8v* lo) {
    const u4v q0 = *(const u4v*)p;
    const u4v q1 = *(const u4v*)(p + 4);
    union { unsigned int u[4]; s8v v; } H, L;
    H.u[0] = __builtin_amdgcn_perm(q0[1], q0[0], 0x05040100);
    L.u[0] = __builtin_amdgcn_perm(q0[1], q0[0], 0x07060302);
    H.u[1] = __builtin_amdgcn_perm(q0[3], q0[2], 0x05040100);
    L.u[1] = __builtin_amdgcn_perm(q0[3], q0[2], 0x07060302);
    H.u[2] = __builtin_amdgcn_perm(q1[1], q1[0], 0x05040100);
    L.u[2] = __builtin_amdgcn_perm(q1[1], q1[0], 0x07060302);
    H.u[3] = __builtin_amdgcn_perm(q1[3], q1[2], 0x05040100);
    L.u[3] = __builtin_amdgcn_perm(q1[3], q1[2], 0x07060302);
    *hi = H.v; *lo = L.v;
}

// async 16B/lane global->LDS (dst = uniform base + lane*16; zero VGPR data cost)
__device__ __forceinline__ void gld16(const unsigned short* g, unsigned int* l) {
    __builtin_amdgcn_global_load_lds(
        (const __attribute__((address_space(1))) void*)(g),
        (__attribute__((address_space(3))) void*)(l), 16, 0, 0);
}

// read fragment j from LDS weight buffer (lane-linear: conflict-free ds_read_b128)
__device__ __forceinline__ s8v ldw(const unsigned int* wb, int j, int l) {
    return *(const s8v*)((const unsigned short*)wb + j * 512 + l * 8);
}

// ---- chunk staging: 15 chunks/step, 32 frags (32KB) each; wave w stages j=4w..4w+3.
// src fragment index (units of 512 shorts) computed against the R14 g_wb layout.
// Plane frag bases: o1h 0, o1l 32, o2h 64, o2l 192, o3h 320, o3l 352,
// am1h 384, am1l 392, am2h 400, am2l 408, am3h 416, am3l 424,
// as1h 432, as1l 440, as2h 448, as2l 456, as3h 464, as3l 472.
template <int C>
__device__ __forceinline__ void stage_chunk(unsigned int* dst, int w, int l) {
#pragma unroll
    for (int i = 0; i < 4; ++i) {
        const int j = w * 4 + i;
        int src;
        if constexpr (C == 0)       // L1: am1h|am1l|as1h|as1l, (j&7)=nt*2+kc
            src = 384 + ((j >> 4) * 48) + (((j >> 3) & 1) * 8) + (j & 7);
        else if constexpr (C == 1)  // L2
            src = 400 + ((j >> 4) * 48) + (((j >> 3) & 1) * 8) + (j & 7);
        else if constexpr (C == 2)  // L3
            src = 416 + ((j >> 4) * 48) + (((j >> 3) & 1) * 8) + (j & 7);
        else if constexpr (C == 3)  // o1 kc0: j<16 h(nt=j), j>=16 l
            src = (j & 15) * 2 + ((j >> 4) * 32);
        else if constexpr (C == 4)  // o1 kc1
            src = (j & 15) * 2 + 1 + ((j >> 4) * 32);
        else if constexpr (C >= 5 && C <= 12)  // o2 kc=C-5: j<16 h(nt=j), j>=16 l
            src = 64 + ((j >> 4) * 128) + ((j & 15) * 8) + (C - 5);
        else if constexpr (C == 13) // o3 kc0-3: j=kc*8+{h:nt, l:4+nt}
            src = 320 + (((j >> 2) & 1) * 32) + ((j & 3) * 8) + (j >> 3);
        else                        // o3 kc4-7
            src = 320 + (((j >> 2) & 1) * 32) + ((j & 3) * 8) + (j >> 3) + 4;
        gld16(g_wb + (size_t)src * 512 + l * 8, dst + j * 256);
    }
}

// swizzle W[K x N] f32 into B-fragment order, split bf16 hi+lo — UNCHANGED from R14
__global__ void prep_kernel(const float* __restrict__ W, int K, int N,
                            int hi_off, int lo_off) {
    const int l = threadIdx.x;
    const int kcN = K >> 5;
    const int nt = blockIdx.x / kcN;
    const int kc = blockIdx.x % kcN;
    const int col = nt * 16 + (l & 15);
    const int k0 = kc * 32 + ((l >> 4) << 3);
    const size_t base = ((size_t)(nt * kcN + kc) * 64 + l) * 8;
#pragma unroll
    for (int b = 0; b < 8; ++b) {
        float wv = W[(size_t)(k0 + b) * N + col];
        unsigned short h = f2b(wv);
        g_wb[hi_off + base + b] = h;
        g_wb[lo_off + base + b] = f2b(wv - b2f(h));
    }
}

#define SWAP_WB() do { unsigned int* _t = wc; wc = wn_; wn_ = _t; } while (0)

extern "C" __global__ void __launch_bounds__(NT)
ode_sac_kernel(const float* __restrict__ y0,
               const float* __restrict__ tarr,
               const float* __restrict__ noise,
               const float* __restrict__ ob1, const float* __restrict__ ob2,
               const float* __restrict__ ob3,
               const float* __restrict__ amb1, const float* __restrict__ amb2,
               const float* __restrict__ amb3,
               const float* __restrict__ asb1, const float* __restrict__ asb2,
               const float* __restrict__ asb3,
               float* __restrict__ out) {
    __shared__ __align__(16) unsigned int y_pk[RB * SYW];    //  8704 B
    __shared__ __align__(16) unsigned int h1_pk[RB * SHW];   // 33280 B
    __shared__ __align__(16) unsigned int h2_pk[RB * SHW];   // 33280 B
    __shared__ __align__(16) unsigned int wbA[8192];         // 32768 B weight buf A
    __shared__ __align__(16) unsigned int wbB[8192];         // 32768 B weight buf B
    unsigned int* a1m = h1_pk;
    unsigned int* a1s = h1_pk + RB * SYW;
    unsigned int* a2m = h2_pk;
    unsigned int* a2s = h2_pk + RB * SYW;

    const int tid = threadIdx.x;
    const int w  = tid >> 6;
    const int l  = tid & 63;
    const int lm = l & 15;
    const int lg = l >> 4;
    const int wm = w >> 2;
    const int wn = w & 3;
    const int row0 = blockIdx.x * RB;
    const int cN = wn * 16 + lm;

    const float dt = tarr[1] - tarr[0];

    // biases
    const float b_am1 = amb1[cN], b_am2 = amb2[cN], b_am3 = amb3[cN];
    const float b_as1 = asb1[cN], b_as2 = asb2[cN], b_as3 = asb3[cN];
    const float b_o3  = ob3[cN];
    const float b_o2a = ob2[(w * 2) * 16 + lm];
    const float b_o2b = ob2[(w * 2 + 1) * 16 + lm];
    float b_o1v[4];
#pragma unroll
    for (int nt = 0; nt < 4; ++nt) b_o1v[nt] = ob1[wn * 64 + nt * 16 + lm];

    // prologue: stage chunk0 + y0 init + out[0]
    stage_chunk<0>(wbA, w, l);
    float ysr[4];
#pragma unroll
    for (int r = 0; r < 4; ++r) {
        const int row = wm * 16 + lg * 4 + r;
        const float v = y0[(size_t)(row0 + row) * DD + cN];
        ysr[r] = v;
        y_pk[row * SYW + cN] = packsplit(v);
        __builtin_nontemporal_store(v, &out[(size_t)(row0 + row) * DD + cN]);
    }
    __syncthreads();
    unsigned int* wc = wbA;
    unsigned int* wn_ = wbB;

    for (int t = 0; t < NSTEP; ++t) {
        float u[4], ep[4];
        f4v accB[4];       // B1 accumulator (spans SP3-SP4)
        f4v acc4[2][2];    // P4 accumulator (spans SP5-SP12)
        f4v f3;            // P5 accumulator (spans SP13-SP14)

        // ================= SP0: P1 (chunk0) =================
        stage_chunk<1>(wn_, w, l);
#pragma unroll
        for (int r = 0; r < 4; ++r) {
            const int row = wm * 16 + lg * 4 + r;
            ep[r] = __builtin_nontemporal_load(
                &noise[(size_t)t * NB * DD + (size_t)(row0 + row) * DD + cN]);
        }
        {
            f4v am = splat4(b_am1), as_ = splat4(b_as1);
#pragma unroll
            for (int kc = 0; kc < 2; ++kc) {
                s8v yh, yl;
                ldsPK(&y_pk[(wm * 16 + lm) * SYW + kc * 32 + lg * 8], &yh, &yl);
                MM3(am, yh, yl, ldw(wc, 2 * wn + kc, l), ldw(wc, 8 + 2 * wn + kc, l));
                MM3(as_, yh, yl, ldw(wc, 16 + 2 * wn + kc, l), ldw(wc, 24 + 2 * wn + kc, l));
            }
#pragma unroll
            for (int r = 0; r < 4; ++r) {
                const int row = wm * 16 + lg * 4 + r;
                a1m[row * SYW + cN] = packsplit(fmaxf(am[r], 0.0f));
                a1s[row * SYW + cN] = packsplit(fmaxf(as_[r], 0.0f));
            }
        }
        __syncthreads(); SWAP_WB();

        // ================= SP1: P2 (chunk1) =================
        stage_chunk<2>(wn_, w, l);
        {
            f4v am = splat4(b_am2), as_ = splat4(b_as2);
#pragma unroll
            for (int kc = 0; kc < 2; ++kc) {
                const int k0 = kc * 32 + lg * 8;
                s8v mh, ml, sh, sl;
                ldsPK(&a1m[(wm * 16 + lm) * SYW + k0], &mh, &ml);
                ldsPK(&a1s[(wm * 16 + lm) * SYW + k0], &sh, &sl);
                MM3(am, mh, ml, ldw(wc, 2 * wn + kc, l), ldw(wc, 8 + 2 * wn + kc, l));
                MM3(as_, sh, sl, ldw(wc, 16 + 2 * wn + kc, l), ldw(wc, 24 + 2 * wn + kc, l));
            }
#pragma unroll
            for (int r = 0; r < 4; ++r) {
                const int row = wm * 16 + lg * 4 + r;
                a2m[row * SYW + cN] = packsplit(fmaxf(am[r], 0.0f));
                a2s[row * SYW + cN] = packsplit(fmaxf(as_[r], 0.0f));
            }
        }
        __syncthreads(); SWAP_WB();

        // ================= SP2: P3 actor -> u (chunk2) =================
        stage_chunk<3>(wn_, w, l);
        {
            f4v m3 = splat4(b_am3), s3 = splat4(b_as3);
#pragma unroll
            for (int kc = 0; kc < 2; ++kc) {
                const int k0 = kc * 32 + lg * 8;
                s8v mh, ml, sh, sl;
                ldsPK(&a2m[(wm * 16 + lm) * SYW + k0], &mh, &ml);
                ldsPK(&a2s[(wm * 16 + lm) * SYW + k0], &sh, &sl);
                MM3(m3, mh, ml, ldw(wc, 2 * wn + kc, l), ldw(wc, 8 + 2 * wn + kc, l));
                MM3(s3, sh, sl, ldw(wc, 16 + 2 * wn + kc, l), ldw(wc, 24 + 2 * wn + kc, l));
            }
#pragma unroll
            for (int r = 0; r < 4; ++r) {
                const float mean = clean_f(fast_tanh(m3[r]));
                const float ls   = clean_f(s3[r]);
                const float sd   = fast_softplus(ls);
                u[r] = fast_tanh(mean + sd * ep[r]);
            }
        }
        __syncthreads(); SWAP_WB();

        // ================= SP3: B1 kc0 (chunk3) =================
        stage_chunk<4>(wn_, w, l);
        {
#pragma unroll
            for (int nt = 0; nt < 4; ++nt) accB[nt] = splat4(b_o1v[nt]);
            s8v yh, yl;
            ldsPK(&y_pk[(wm * 16 + lm) * SYW + 0 * 32 + lg * 8], &yh, &yl);
#pragma unroll
            for (int nt = 0; nt < 4; ++nt)
                MM3(accB[nt], yh, yl, ldw(wc, 4 * wn + nt, l), ldw(wc, 16 + 4 * wn + nt, l));
        }
        __syncthreads(); SWAP_WB();

        // ================= SP4: B1 kc1 + h1 store (chunk4) =================
        stage_chunk<5>(wn_, w, l);
        {
            s8v yh, yl;
            ldsPK(&y_pk[(wm * 16 + lm) * SYW + 1 * 32 + lg * 8], &yh, &yl);
#pragma unroll
            for (int nt = 0; nt < 4; ++nt)
                MM3(accB[nt], yh, yl, ldw(wc, 4 * wn + nt, l), ldw(wc, 16 + 4 * wn + nt, l));
#pragma unroll
            for (int nt = 0; nt < 4; ++nt)
#pragma unroll
                for (int r = 0; r < 4; ++r) {
                    const int row = wm * 16 + lg * 4 + r;
                    const int col = wn * 64 + nt * 16 + lm;
                    h1_pk[row * SHW + col] = packsplit(fast_tanh(accB[nt][r]));
                }
        }
        __syncthreads(); SWAP_WB();

        // ================= SP5..SP12: P4 kc q=0..7 (chunks 5..12) =================
        acc4[0][0] = splat4(b_o2a); acc4[0][1] = splat4(b_o2b);
        acc4[1][0] = splat4(b_o2a); acc4[1][1] = splat4(b_o2b);
#define P4_BODY(Q)                                                            \
        {                                                                     \
            const int k0 = (Q) * 32 + lg * 8;                                 \
            s8v a0h, a0l, a1h_, a1l_;                                         \
            ldsPK(&h1_pk[(0 * 16 + lm) * SHW + k0], &a0h, &a0l);              \
            ldsPK(&h1_pk[(1 * 16 + lm) * SHW + k0], &a1h_, &a1l_);            \
            const s8v bh0 = ldw(wc, 2 * w, l),     bl0 = ldw(wc, 16 + 2 * w, l); \
            const s8v bh1 = ldw(wc, 2 * w + 1, l), bl1 = ldw(wc, 17 + 2 * w, l); \
            MM3(acc4[0][0], a0h, a0l, bh0, bl0);                              \
            MM3(acc4[0][1], a0h, a0l, bh1, bl1);                              \
            MM3(acc4[1][0], a1h_, a1l_, bh0, bl0);                            \
            MM3(acc4[1][1], a1h_, a1l_, bh1, bl1);                            \
        }
        stage_chunk<6>(wn_, w, l);  P4_BODY(0) __syncthreads(); SWAP_WB();
        stage_chunk<7>(wn_, w, l);  P4_BODY(1) __syncthreads(); SWAP_WB();
        stage_chunk<8>(wn_, w, l);  P4_BODY(2) __syncthreads(); SWAP_WB();
        stage_chunk<9>(wn_, w, l);  P4_BODY(3) __syncthreads(); SWAP_WB();
        stage_chunk<10>(wn_, w, l); P4_BODY(4) __syncthreads(); SWAP_WB();
        stage_chunk<11>(wn_, w, l); P4_BODY(5) __syncthreads(); SWAP_WB();
        stage_chunk<12>(wn_, w, l); P4_BODY(6) __syncthreads(); SWAP_WB();
        // SP12: last kc + softplus + h2 store (chunk12)
        stage_chunk<13>(wn_, w, l);
        P4_BODY(7)
        {
#pragma unroll
            for (int mt = 0; mt < 2; ++mt)
#pragma unroll
                for (int ct = 0; ct < 2; ++ct)
#pragma unroll
                    for (int r = 0; r < 4; ++r) {
                        const int row = mt * 16 + lg * 4 + r;
                        const int col = (w * 2 + ct) * 16 + lm;
                        h2_pk[row * SHW + col] = packsplit(fast_softplus(acc4[mt][ct][r]));
                    }
        }
        __syncthreads(); SWAP_WB();

        // ================= SP13: P5 kc0..3 (chunk13) =================
        stage_chunk<14>(wn_, w, l);
        f3 = splat4(b_o3);
#pragma unroll
        for (int kc = 0; kc < 4; ++kc) {
            s8v ah, al;
            ldsPK(&h2_pk[(wm * 16 + lm) * SHW + kc * 32 + lg * 8], &ah, &al);
            MM3(f3, ah, al, ldw(wc, kc * 8 + wn, l), ldw(wc, kc * 8 + 4 + wn, l));
        }
        __syncthreads(); SWAP_WB();

        // ================= SP14: P5 kc4..7 + y update + out (chunk14) =================
        stage_chunk<0>(wn_, w, l);   // next step's chunk0
#pragma unroll
        for (int kc = 4; kc < 8; ++kc) {
            s8v ah, al;
            ldsPK(&h2_pk[(wm * 16 + lm) * SHW + kc * 32 + lg * 8], &ah, &al);
            MM3(f3, ah, al, ldw(wc, (kc - 4) * 8 + wn, l), ldw(wc, (kc - 4) * 8 + 4 + wn, l));
        }
#pragma unroll
        for (int r = 0; r < 4; ++r) {
            const int row = wm * 16 + lg * 4 + r;
            const float yn = ysr[r] + (f3[r] - u[r]) * dt;
            ysr[r] = yn;
            y_pk[row * SYW + cN] = packsplit(yn);
            __builtin_nontemporal_store(yn,
                &out[(size_t)(t + 1) * NB * DD + (size_t)(row0 + row) * DD + cN]);
        }
        __syncthreads(); SWAP_WB();
    }
}

extern "C" void kernel_launch(void* const* d_in, const int* in_sizes, int n_in,
                              void* d_out, int out_size, void* d_ws, size_t ws_size,
                              hipStream_t stream) {
    const float* y0    = (const float*)d_in[0];
    const float* tarr  = (const float*)d_in[1];
    const float* noise = (const float*)d_in[2];
    const float* oW1 = (const float*)d_in[3];  const float* ob1 = (const float*)d_in[4];
    const float* oW2 = (const float*)d_in[5];  const float* ob2 = (const float*)d_in[6];
    const float* oW3 = (const float*)d_in[7];  const float* ob3 = (const float*)d_in[8];
    const float* amW1 = (const float*)d_in[9];  const float* amb1 = (const float*)d_in[10];
    const float* amW2 = (const float*)d_in[11]; const float* amb2 = (const float*)d_in[12];
    const float* amW3 = (const float*)d_in[13]; const float* amb3 = (const float*)d_in[14];
    const float* asW1 = (const float*)d_in[15]; const float* asb1 = (const float*)d_in[16];
    const float* asW2 = (const float*)d_in[17]; const float* asb2 = (const float*)d_in[18];
    const float* asW3 = (const float*)d_in[19]; const float* asb3 = (const float*)d_in[20];
    float* out = (float*)d_out;

    hipLaunchKernelGGL(prep_kernel, dim3(16 * 2), dim3(64), 0, stream, oW1, 64, 256, O1H, O1L);
    hipLaunchKernelGGL(prep_kernel, dim3(16 * 8), dim3(64), 0, stream, oW2, 256, 256, O2H, O2L);
    hipLaunchKernelGGL(prep_kernel, dim3(4 * 8),  dim3(64), 0, stream, oW3, 256, 64, O3H, O3L);
    hipLaunchKernelGGL(prep_kernel, dim3(4 * 2),  dim3(64), 0, stream, amW1, 64, 64, AM1H, AM1L);
    hipLaunchKernelGGL(prep_kernel, dim3(4 * 2),  dim3(64), 0, stream, amW2, 64, 64, AM2H, AM2L);
    hipLaunchKernelGGL(prep_kernel, dim3(4 * 2),  dim3(64), 0, stream, amW3, 64, 64, AM3H, AM3L);
    hipLaunchKernelGGL(prep_kernel, dim3(4 * 2),  dim3(64), 0, stream, asW1, 64, 64, AS1H, AS1L);
    hipLaunchKernelGGL(prep_kernel, dim3(4 * 2),  dim3(64), 0, stream, asW2, 64, 64, AS2H, AS2L);
    hipLaunchKernelGGL(prep_kernel, dim3(4 * 2),  dim3(64), 0, stream, asW3, 64, 64, AS3H, AS3L);

    hipLaunchKernelGGL(ode_sac_kernel, dim3(NB / RB), dim3(NT), 0, stream,
                       y0, tarr, noise,
                       ob1, ob2, ob3, amb1, amb2, amb3, asb1, asb2, asb3,
                       out);
}